// Round 1
// baseline (636.077 us; speedup 1.0000x reference)
//
#include <hip/hip_runtime.h>
#include <hip/hip_bf16.h>

// WindowAttention: B=2048 windows, N=64 tokens, DIM=256, 1 head, scale=1/16.
// Pipeline: prep (bias table + proj_w->bf16) -> qkv_gemm (bf16 MFMA, QKV to ws)
//           -> attn_proj (per-window attention + fused proj).

typedef __bf16 bf16x8_t __attribute__((ext_vector_type(8)));
typedef __bf16 bf16x4_t __attribute__((ext_vector_type(4)));
typedef float floatx4_t __attribute__((ext_vector_type(4)));

#define MFMA16(a, b, c) __builtin_amdgcn_mfma_f32_16x16x32_bf16(a, b, c, 0, 0, 0)

// ---------------- prep: bias table (64x64) + proj_w -> bf16 ----------------
__global__ __launch_bounds__(256) void prep_kernel(
    const float* __restrict__ theta_max, const float* __restrict__ a_p,
    const float* __restrict__ b_p, const float* __restrict__ a_r,
    const float* __restrict__ b_r, const float* __restrict__ proj_w,
    float* __restrict__ bias_ws, __bf16* __restrict__ pw_bf) {
  int t = blockIdx.x * 256 + threadIdx.x;
  if (t < 4096) {
    int i = t >> 6, j = t & 63;
    int chi = i >> 3, cwi = i & 7;
    int chj = j >> 3, cwj = j & 7;
    int rad = chi - chj, az = cwi - cwj;
    int azm = ((az % 15) + 15) % 15;
    int rdm = ((rad % 15) + 15) % 15;
    float az_ang = (float)az * 0.09817477042468103f;  // 2*pi/64
    float tm = theta_max[j >> 3];                      // tmax broadcasts over COLUMN j
    float r_ang = (float)rad * tm * (1.0f / 64.0f);
    bias_ws[t] = a_p[azm] * cosf(az_ang) + b_p[azm] * sinf(az_ang) +
                 a_r[rdm] * cosf(r_ang) + b_r[rdm] * sinf(r_ang);
  } else {
    int id = t - 4096;
    if (id < 65536) pw_bf[id] = (__bf16)proj_w[id];
  }
}

// ---------------- QKV GEMM: (131072x256) @ (256x768)^T -> bf16 Q/K/V -------
// 128x128 tile, 4 waves of 64x64, BK=64, fp32->bf16 convert during staging.
__global__ __launch_bounds__(256, 2) void qkv_gemm_kernel(
    const float* __restrict__ x, const float* __restrict__ qkv_w,
    const float* __restrict__ qkv_b, __bf16* __restrict__ Qd,
    __bf16* __restrict__ Kd, __bf16* __restrict__ Vd) {
  __shared__ __align__(16) __bf16 aTile[128 * 72];  // pitch 72 (pad 8) -> 2-way max
  __shared__ __align__(16) __bf16 bTile[128 * 72];
  const int tid = threadIdx.x;
  const int bm = blockIdx.y, bn = blockIdx.x;
  const int lane = tid & 63, wave = tid >> 6;
  const int wm = (wave >> 1) * 64, wn = (wave & 1) * 64;
  const int l15 = lane & 15, quad = lane >> 4;

  floatx4_t acc[4][4] = {};

  for (int kt = 0; kt < 4; ++kt) {
#pragma unroll
    for (int i = 0; i < 8; ++i) {
      int ch = tid + i * 256;
      int row = ch >> 4, c4 = (ch & 15) * 4;
      float4 fa = *reinterpret_cast<const float4*>(
          &x[(size_t)(bm * 128 + row) * 256 + kt * 64 + c4]);
      float4 fb = *reinterpret_cast<const float4*>(
          &qkv_w[(size_t)(bn * 128 + row) * 256 + kt * 64 + c4]);
      bf16x4_t ha, hb;
      ha[0] = (__bf16)fa.x; ha[1] = (__bf16)fa.y;
      ha[2] = (__bf16)fa.z; ha[3] = (__bf16)fa.w;
      hb[0] = (__bf16)fb.x; hb[1] = (__bf16)fb.y;
      hb[2] = (__bf16)fb.z; hb[3] = (__bf16)fb.w;
      *reinterpret_cast<bf16x4_t*>(&aTile[row * 72 + c4]) = ha;
      *reinterpret_cast<bf16x4_t*>(&bTile[row * 72 + c4]) = hb;
    }
    __syncthreads();
#pragma unroll
    for (int kc = 0; kc < 2; ++kc) {
      bf16x8_t af[4], bfr[4];
#pragma unroll
      for (int r = 0; r < 4; ++r)
        af[r] = *reinterpret_cast<const bf16x8_t*>(
            &aTile[(wm + r * 16 + l15) * 72 + kc * 32 + quad * 8]);
#pragma unroll
      for (int c = 0; c < 4; ++c)
        bfr[c] = *reinterpret_cast<const bf16x8_t*>(
            &bTile[(wn + c * 16 + l15) * 72 + kc * 32 + quad * 8]);
#pragma unroll
      for (int r = 0; r < 4; ++r)
#pragma unroll
        for (int c = 0; c < 4; ++c) acc[r][c] = MFMA16(af[r], bfr[c], acc[r][c]);
    }
    __syncthreads();
  }
  // epilogue: n<256 -> Q, <512 -> K, else V (128-tiles never straddle a 256 boundary)
#pragma unroll
  for (int c = 0; c < 4; ++c) {
    int n = bn * 128 + wn + c * 16 + l15;
    __bf16* outp = (n < 256) ? Qd : (n < 512) ? Kd : Vd;
    int d = n & 255;
    float bias = qkv_b[n];
#pragma unroll
    for (int r = 0; r < 4; ++r) {
      int m0 = bm * 128 + wm + r * 16 + quad * 4;
#pragma unroll
      for (int g = 0; g < 4; ++g)
        outp[(size_t)(m0 + g) * 256 + d] = (__bf16)(acc[r][c][g] + bias);
    }
  }
}

// ---------------- attention + proj, one block (4 waves) per window ----------
#define KP 264  // pitch for K / O tiles (256 + 8)
#define VP 72   // pitch for vT / P tiles (64 + 8)
__global__ __launch_bounds__(256, 2) void attn_proj_kernel(
    const __bf16* __restrict__ Qd, const __bf16* __restrict__ Kd,
    const __bf16* __restrict__ Vd, const float* __restrict__ bias_ws,
    const __bf16* __restrict__ pw_bf, const float* __restrict__ proj_b,
    float* __restrict__ out) {
  // ldsA phase-reused: K(64x264) -> vT(256x72) -> O(64x264); max 18432 elements
  __shared__ __align__(16) __bf16 ldsA[256 * 72];
  __shared__ __align__(16) __bf16 ldsP[64 * 72];
  const int b = blockIdx.x;
  const size_t base = (size_t)b * 64 * 256;
  const int tid = threadIdx.x;
  const int lane = tid & 63, wave = tid >> 6;
  const int l15 = lane & 15, quad = lane >> 4;

  // stage K rows (vectorized, conflict-free)
#pragma unroll
  for (int i = 0; i < 8; ++i) {
    int ch = tid + i * 256;
    int n = ch >> 5, d0 = (ch & 31) * 8;
    *reinterpret_cast<bf16x8_t*>(&ldsA[n * KP + d0]) =
        *reinterpret_cast<const bf16x8_t*>(&Kd[base + n * 256 + d0]);
  }
  // Q fragments straight from global (rows wave*16..+16)
  bf16x8_t qf[8];
#pragma unroll
  for (int kc = 0; kc < 8; ++kc)
    qf[kc] = *reinterpret_cast<const bf16x8_t*>(
        &Qd[base + (wave * 16 + l15) * 256 + kc * 32 + quad * 8]);
  __syncthreads();

  // S = (Q K^T) * scale + bias ; rows wave*16..+16 x 64 cols
  floatx4_t accs[4] = {};
#pragma unroll
  for (int ct = 0; ct < 4; ++ct)
#pragma unroll
    for (int kc = 0; kc < 8; ++kc) {
      bf16x8_t bfr = *reinterpret_cast<const bf16x8_t*>(
          &ldsA[(ct * 16 + l15) * KP + kc * 32 + quad * 8]);
      accs[ct] = MFMA16(qf[kc], bfr, accs[ct]);
    }

  // softmax per row (row = wave*16 + quad*4 + g lives in the quad's 16 lanes)
  float p[4][4];
#pragma unroll
  for (int ct = 0; ct < 4; ++ct)
#pragma unroll
    for (int g = 0; g < 4; ++g) {
      int row = wave * 16 + quad * 4 + g;
      p[ct][g] = accs[ct][g] * 0.0625f + bias_ws[row * 64 + ct * 16 + l15];
    }
#pragma unroll
  for (int g = 0; g < 4; ++g) {
    float m = fmaxf(fmaxf(p[0][g], p[1][g]), fmaxf(p[2][g], p[3][g]));
#pragma unroll
    for (int off = 1; off < 16; off <<= 1) m = fmaxf(m, __shfl_xor(m, off, 64));
    float l = 0.f;
#pragma unroll
    for (int ct = 0; ct < 4; ++ct) {
      p[ct][g] = __expf(p[ct][g] - m);
      l += p[ct][g];
    }
#pragma unroll
    for (int off = 1; off < 16; off <<= 1) l += __shfl_xor(l, off, 64);
    float inv = 1.0f / l;
    int row = wave * 16 + quad * 4 + g;
#pragma unroll
    for (int ct = 0; ct < 4; ++ct)
      ldsP[row * VP + ct * 16 + l15] = (__bf16)(p[ct][g] * inv);
  }
  __syncthreads();  // K reads done by all waves; P visible

  // stage V transposed: vT[c][j], vectorized LDS writes
#pragma unroll
  for (int i = 0; i < 8; ++i) {
    int id = tid + i * 256;
    int c = id & 255, j0 = (id >> 8) * 8;
    bf16x8_t tmp;
#pragma unroll
    for (int jj = 0; jj < 8; ++jj) tmp[jj] = Vd[base + (j0 + jj) * 256 + c];
    *reinterpret_cast<bf16x8_t*>(&ldsA[c * VP + j0]) = tmp;
  }
  __syncthreads();

  // O = P @ V : rows wave*16..+16 x 256 cols
  floatx4_t acco[16] = {};
#pragma unroll
  for (int kc = 0; kc < 2; ++kc) {
    bf16x8_t af = *reinterpret_cast<const bf16x8_t*>(
        &ldsP[(wave * 16 + l15) * VP + kc * 32 + quad * 8]);
#pragma unroll
    for (int ct = 0; ct < 16; ++ct) {
      bf16x8_t bfr = *reinterpret_cast<const bf16x8_t*>(
          &ldsA[(ct * 16 + l15) * VP + kc * 32 + quad * 8]);
      acco[ct] = MFMA16(af, bfr, acco[ct]);
    }
  }
  __syncthreads();  // vT reads done
  // O (C-layout) -> LDS bf16 (A-layout source for proj)
#pragma unroll
  for (int ct = 0; ct < 16; ++ct)
#pragma unroll
    for (int g = 0; g < 4; ++g) {
      int row = wave * 16 + quad * 4 + g;
      ldsA[row * KP + ct * 16 + l15] = (__bf16)acco[ct][g];
    }
  __syncthreads();

  // proj: out = O @ proj_w^T + proj_b ; proj_w bf16 streamed from L2
  floatx4_t accp[16] = {};
#pragma unroll
  for (int kc = 0; kc < 8; ++kc) {
    bf16x8_t af = *reinterpret_cast<const bf16x8_t*>(
        &ldsA[(wave * 16 + l15) * KP + kc * 32 + quad * 8]);
#pragma unroll
    for (int ct = 0; ct < 16; ++ct) {
      bf16x8_t bfr = *reinterpret_cast<const bf16x8_t*>(
          &pw_bf[(ct * 16 + l15) * 256 + kc * 32 + quad * 8]);
      accp[ct] = MFMA16(af, bfr, accp[ct]);
    }
  }
#pragma unroll
  for (int ct = 0; ct < 16; ++ct) {
    int col = ct * 16 + l15;
    float pbv = proj_b[col];
#pragma unroll
    for (int g = 0; g < 4; ++g) {
      int row = wave * 16 + quad * 4 + g;
      out[base + row * 256 + col] = accp[ct][g] + pbv;
    }
  }
}

extern "C" void kernel_launch(void* const* d_in, const int* in_sizes, int n_in,
                              void* d_out, int out_size, void* d_ws, size_t ws_size,
                              hipStream_t stream) {
  const float* x = (const float*)d_in[0];
  const float* theta_max = (const float*)d_in[1];
  const float* qkv_w = (const float*)d_in[2];
  const float* qkv_b = (const float*)d_in[3];
  const float* proj_w = (const float*)d_in[4];
  const float* proj_b = (const float*)d_in[5];
  const float* a_p = (const float*)d_in[6];
  const float* b_p = (const float*)d_in[7];
  const float* a_r = (const float*)d_in[8];
  const float* b_r = (const float*)d_in[9];
  float* out = (float*)d_out;

  char* ws = (char*)d_ws;
  float* bias_ws = (float*)ws;                          // 16384 B
  __bf16* pw_bf = (__bf16*)(ws + 16384);                // 131072 B
  __bf16* Qb = (__bf16*)(ws + 147456);                  // 3 x 67108864 B
  __bf16* Kb = (__bf16*)(ws + 147456 + 67108864);
  __bf16* Vb = (__bf16*)(ws + 147456 + 2 * 67108864);

  hipLaunchKernelGGL(prep_kernel, dim3(272), dim3(256), 0, stream,
                     theta_max, a_p, b_p, a_r, b_r, proj_w, bias_ws, pw_bf);
  hipLaunchKernelGGL(qkv_gemm_kernel, dim3(6, 1024), dim3(256), 0, stream,
                     x, qkv_w, qkv_b, Qb, Kb, Vb);
  hipLaunchKernelGGL(attn_proj_kernel, dim3(2048), dim3(256), 0, stream,
                     Qb, Kb, Vb, bias_ws, pw_bf, proj_b, out);
}

// Round 2
// 465.739 us; speedup vs baseline: 1.3657x; 1.3657x over previous
//
#include <hip/hip_runtime.h>
#include <hip/hip_bf16.h>

// WindowAttention B=2048, N=64, DIM=256, 1 head, scale=1/16.
// prep (convert x/w -> bf16, bias table) -> qkv_gemm (async-LDS MFMA, V transposed)
// -> attn (S+softmax+PV, one barrier) -> proj_gemm.
// Q,K parked in d_out (dead before proj writes); Ob aliases xb.

typedef __bf16 bf16x8_t __attribute__((ext_vector_type(8)));
typedef float floatx4_t __attribute__((ext_vector_type(4)));

#define MFMA16(a, b, c) __builtin_amdgcn_mfma_f32_16x16x32_bf16(a, b, c, 0, 0, 0)
#define NTOK 131072  // 2048 windows * 64 tokens

__device__ __forceinline__ void gld_lds16(const void* g, void* l) {
  __builtin_amdgcn_global_load_lds(
      (const __attribute__((address_space(1))) unsigned int*)g,
      (__attribute__((address_space(3))) unsigned int*)l, 16, 0, 0);
}

__device__ __forceinline__ void cvt8(const float* src, __bf16* dst) {
  float4 f0 = reinterpret_cast<const float4*>(src)[0];
  float4 f1 = reinterpret_cast<const float4*>(src)[1];
  bf16x8_t h;
  h[0] = (__bf16)f0.x; h[1] = (__bf16)f0.y; h[2] = (__bf16)f0.z; h[3] = (__bf16)f0.w;
  h[4] = (__bf16)f1.x; h[5] = (__bf16)f1.y; h[6] = (__bf16)f1.z; h[7] = (__bf16)f1.w;
  *reinterpret_cast<bf16x8_t*>(dst) = h;
}

// ------------- prep: x->bf16, qkv_w->bf16, proj_w->bf16, bias table --------
__global__ __launch_bounds__(256) void prep_kernel(
    const float* __restrict__ x, const float* __restrict__ qkv_w,
    const float* __restrict__ proj_w, const float* __restrict__ theta_max,
    const float* __restrict__ a_p, const float* __restrict__ b_p,
    const float* __restrict__ a_r, const float* __restrict__ b_r,
    __bf16* __restrict__ xb, __bf16* __restrict__ wb, __bf16* __restrict__ pwb,
    float* __restrict__ bias_ws) {
  int blk = blockIdx.x, tid = threadIdx.x;
  if (blk < 16384) {
    int t = blk * 256 + tid;
    cvt8(&x[(size_t)t * 8], &xb[(size_t)t * 8]);
  } else if (blk < 16480) {
    int t = (blk - 16384) * 256 + tid;
    cvt8(&qkv_w[(size_t)t * 8], &wb[(size_t)t * 8]);
  } else if (blk < 16512) {
    int t = (blk - 16480) * 256 + tid;
    cvt8(&proj_w[(size_t)t * 8], &pwb[(size_t)t * 8]);
  } else {
    int t = (blk - 16512) * 256 + tid;  // 0..4095
    int i = t >> 6, j = t & 63;
    int rad = (i >> 3) - (j >> 3), az = (i & 7) - (j & 7);
    int azm = ((az % 15) + 15) % 15;
    int rdm = ((rad % 15) + 15) % 15;
    float az_ang = (float)az * 0.09817477042468103f;  // 2*pi/64
    float tm = theta_max[j >> 3];                     // broadcasts over column j
    float r_ang = (float)rad * tm * (1.0f / 64.0f);
    bias_ws[t] = a_p[azm] * cosf(az_ang) + b_p[azm] * sinf(az_ang) +
                 a_r[rdm] * cosf(r_ang) + b_r[rdm] * sinf(r_ang);
  }
}

// ---------------- QKV GEMM: (131072x256)bf16 @ (768x256)^T -----------------
// 128x128 tile, BK=64, async global->LDS (16B), XOR-swizzled LDS (no pad).
__global__ __launch_bounds__(256, 4) void qkv_gemm_kernel(
    const __bf16* __restrict__ xb, const __bf16* __restrict__ wb,
    const float* __restrict__ qkv_b, __bf16* __restrict__ Qd,
    __bf16* __restrict__ Kd, __bf16* __restrict__ Vt) {
  __shared__ __align__(16) __bf16 aT[128 * 64];  // 16 KB, swizzled chunks
  __shared__ __align__(16) __bf16 bT[128 * 64];
  const int tid = threadIdx.x;
  const int bn = blockIdx.x, bm = blockIdx.y;
  const int lane = tid & 63, wave = tid >> 6;
  const int wm = (wave >> 1) * 64, wn = (wave & 1) * 64;
  const int l15 = lane & 15, quad = lane >> 4;

  floatx4_t acc[4][4] = {};

  for (int kt = 0; kt < 4; ++kt) {
#pragma unroll
    for (int i = 0; i < 4; ++i) {
      int L = tid + i * 256;               // chunk id 0..1023
      int row = L >> 3, sc = L & 7, c8 = sc ^ (row & 7);
      gld_lds16(&xb[(size_t)(bm * 128 + row) * 256 + kt * 64 + c8 * 8], &aT[L * 8]);
      gld_lds16(&wb[(size_t)(bn * 128 + row) * 256 + kt * 64 + c8 * 8], &bT[L * 8]);
    }
    __syncthreads();
#pragma unroll
    for (int kc = 0; kc < 2; ++kc) {
      bf16x8_t af[4], bfr[4];
#pragma unroll
      for (int r = 0; r < 4; ++r) {
        int row = wm + r * 16 + l15, c8 = kc * 4 + quad, sc = c8 ^ (row & 7);
        af[r] = *reinterpret_cast<const bf16x8_t*>(&aT[(row * 8 + sc) * 8]);
      }
#pragma unroll
      for (int c = 0; c < 4; ++c) {
        int row = wn + c * 16 + l15, c8 = kc * 4 + quad, sc = c8 ^ (row & 7);
        bfr[c] = *reinterpret_cast<const bf16x8_t*>(&bT[(row * 8 + sc) * 8]);
      }
#pragma unroll
      for (int r = 0; r < 4; ++r)
#pragma unroll
        for (int c = 0; c < 4; ++c) acc[r][c] = MFMA16(af[r], bfr[c], acc[r][c]);
    }
    __syncthreads();
  }
  // epilogue: n<256 -> Q row-major, <512 -> K row-major, else V TRANSPOSED
#pragma unroll
  for (int c = 0; c < 4; ++c) {
    int n = bn * 128 + wn + c * 16 + l15;
    float bias = qkv_b[n];
    if (n < 512) {
      __bf16* outp = (n < 256) ? Qd : Kd;
      int d = n & 255;
#pragma unroll
      for (int r = 0; r < 4; ++r) {
        int m0 = bm * 128 + wm + r * 16 + quad * 4;
#pragma unroll
        for (int g = 0; g < 4; ++g)
          outp[(size_t)(m0 + g) * 256 + d] = (__bf16)(acc[r][c][g] + bias);
      }
    } else {
      int d = n - 512;
#pragma unroll
      for (int r = 0; r < 4; ++r) {
        int m0 = bm * 128 + wm + r * 16 + quad * 4;
#pragma unroll
        for (int g = 0; g < 4; ++g)
          Vt[(size_t)d * NTOK + m0 + g] = (__bf16)(acc[r][c][g] + bias);
      }
    }
  }
}

// ---------------- attention (no proj): one block per window ------------------
#define VPITCH 72
__global__ __launch_bounds__(256, 2) void attn_kernel(
    const __bf16* __restrict__ Qd, const __bf16* __restrict__ Kd,
    const __bf16* __restrict__ Vt, const float* __restrict__ bias_ws,
    __bf16* __restrict__ Ob) {
  __shared__ __align__(16) __bf16 ldsV[256 * 64];    // 32 KB swizzled (n=d, k=token)
  __shared__ __align__(16) __bf16 ldsP[64 * VPITCH]; // 9 KB
  const int b = blockIdx.x;
  const size_t base = (size_t)b * 64 * 256;
  const int tid = threadIdx.x;
  const int lane = tid & 63, wave = tid >> 6;
  const int l15 = lane & 15, quad = lane >> 4;

  // async stage V^T rows (d-major); swizzle chunks within each 128B row
#pragma unroll
  for (int i = 0; i < 8; ++i) {
    int L = tid + i * 256;                 // 2048 chunks
    int c = L >> 3, sc = L & 7, j8 = sc ^ (c & 7);
    gld_lds16(&Vt[(size_t)c * NTOK + b * 64 + j8 * 8], &ldsV[L * 8]);
  }

  // Q fragments direct from global (own 16 rows)
  bf16x8_t qf[8];
#pragma unroll
  for (int kc = 0; kc < 8; ++kc)
    qf[kc] = *reinterpret_cast<const bf16x8_t*>(
        &Qd[base + (wave * 16 + l15) * 256 + kc * 32 + quad * 8]);

  // S = (Q K^T)*scale + bias ; K fragments direct from global
  floatx4_t accs[4] = {};
#pragma unroll
  for (int ct = 0; ct < 4; ++ct)
#pragma unroll
    for (int kc = 0; kc < 8; ++kc) {
      bf16x8_t bfr = *reinterpret_cast<const bf16x8_t*>(
          &Kd[base + (ct * 16 + l15) * 256 + kc * 32 + quad * 8]);
      accs[ct] = MFMA16(qf[kc], bfr, accs[ct]);
    }

  // softmax per row (C-layout: row = wave*16 + quad*4 + g, col = ct*16 + l15)
  float p[4][4];
#pragma unroll
  for (int ct = 0; ct < 4; ++ct)
#pragma unroll
    for (int g = 0; g < 4; ++g) {
      int row = wave * 16 + quad * 4 + g;
      p[ct][g] = accs[ct][g] * 0.0625f + bias_ws[row * 64 + ct * 16 + l15];
    }
#pragma unroll
  for (int g = 0; g < 4; ++g) {
    float m = fmaxf(fmaxf(p[0][g], p[1][g]), fmaxf(p[2][g], p[3][g]));
#pragma unroll
    for (int off = 1; off < 16; off <<= 1) m = fmaxf(m, __shfl_xor(m, off, 64));
    float l = 0.f;
#pragma unroll
    for (int ct = 0; ct < 4; ++ct) {
      p[ct][g] = __expf(p[ct][g] - m);
      l += p[ct][g];
    }
#pragma unroll
    for (int off = 1; off < 16; off <<= 1) l += __shfl_xor(l, off, 64);
    float inv = 1.0f / l;
    int row = wave * 16 + quad * 4 + g;
#pragma unroll
    for (int ct = 0; ct < 4; ++ct)
      ldsP[row * VPITCH + ct * 16 + l15] = (__bf16)(p[ct][g] * inv);
  }
  __syncthreads();  // V staged + P visible (each wave reads only its own P rows)

  // O = P @ V : A = own P rows, B = ldsV (n=d, k=token)
  floatx4_t acco[16] = {};
#pragma unroll
  for (int kc = 0; kc < 2; ++kc) {
    bf16x8_t af = *reinterpret_cast<const bf16x8_t*>(
        &ldsP[(wave * 16 + l15) * VPITCH + kc * 32 + quad * 8]);
#pragma unroll
    for (int ct = 0; ct < 16; ++ct) {
      int n = ct * 16 + l15, c8 = kc * 4 + quad, sc = c8 ^ (n & 7);
      bf16x8_t bfr = *reinterpret_cast<const bf16x8_t*>(&ldsV[(n * 8 + sc) * 8]);
      acco[ct] = MFMA16(af, bfr, acco[ct]);
    }
  }
#pragma unroll
  for (int ct = 0; ct < 16; ++ct) {
    int col = ct * 16 + l15;
#pragma unroll
    for (int g = 0; g < 4; ++g) {
      int row = wave * 16 + quad * 4 + g;
      Ob[base + row * 256 + col] = (__bf16)acco[ct][g];
    }
  }
}

// ---------------- proj GEMM: (131072x256)bf16 @ (256x256)^T + b -> fp32 ----
__global__ __launch_bounds__(256, 4) void proj_gemm_kernel(
    const __bf16* __restrict__ Ob, const __bf16* __restrict__ pwb,
    const float* __restrict__ proj_b, float* __restrict__ out) {
  __shared__ __align__(16) __bf16 aT[128 * 64];
  __shared__ __align__(16) __bf16 bT[128 * 64];
  const int tid = threadIdx.x;
  const int bn = blockIdx.x, bm = blockIdx.y;
  const int lane = tid & 63, wave = tid >> 6;
  const int wm = (wave >> 1) * 64, wn = (wave & 1) * 64;
  const int l15 = lane & 15, quad = lane >> 4;

  floatx4_t acc[4][4] = {};

  for (int kt = 0; kt < 4; ++kt) {
#pragma unroll
    for (int i = 0; i < 4; ++i) {
      int L = tid + i * 256;
      int row = L >> 3, sc = L & 7, c8 = sc ^ (row & 7);
      gld_lds16(&Ob[(size_t)(bm * 128 + row) * 256 + kt * 64 + c8 * 8], &aT[L * 8]);
      gld_lds16(&pwb[(size_t)(bn * 128 + row) * 256 + kt * 64 + c8 * 8], &bT[L * 8]);
    }
    __syncthreads();
#pragma unroll
    for (int kc = 0; kc < 2; ++kc) {
      bf16x8_t af[4], bfr[4];
#pragma unroll
      for (int r = 0; r < 4; ++r) {
        int row = wm + r * 16 + l15, c8 = kc * 4 + quad, sc = c8 ^ (row & 7);
        af[r] = *reinterpret_cast<const bf16x8_t*>(&aT[(row * 8 + sc) * 8]);
      }
#pragma unroll
      for (int c = 0; c < 4; ++c) {
        int row = wn + c * 16 + l15, c8 = kc * 4 + quad, sc = c8 ^ (row & 7);
        bfr[c] = *reinterpret_cast<const bf16x8_t*>(&bT[(row * 8 + sc) * 8]);
      }
#pragma unroll
      for (int r = 0; r < 4; ++r)
#pragma unroll
        for (int c = 0; c < 4; ++c) acc[r][c] = MFMA16(af[r], bfr[c], acc[r][c]);
    }
    __syncthreads();
  }
#pragma unroll
  for (int c = 0; c < 4; ++c) {
    int n = bn * 128 + wn + c * 16 + l15;
    float pbv = proj_b[n];
#pragma unroll
    for (int r = 0; r < 4; ++r) {
      int m0 = bm * 128 + wm + r * 16 + quad * 4;
#pragma unroll
      for (int g = 0; g < 4; ++g)
        out[(size_t)(m0 + g) * 256 + n] = acc[r][c][g] + pbv;
    }
  }
}

extern "C" void kernel_launch(void* const* d_in, const int* in_sizes, int n_in,
                              void* d_out, int out_size, void* d_ws, size_t ws_size,
                              hipStream_t stream) {
  const float* x = (const float*)d_in[0];
  const float* theta_max = (const float*)d_in[1];
  const float* qkv_w = (const float*)d_in[2];
  const float* qkv_b = (const float*)d_in[3];
  const float* proj_w = (const float*)d_in[4];
  const float* proj_b = (const float*)d_in[5];
  const float* a_p = (const float*)d_in[6];
  const float* b_p = (const float*)d_in[7];
  const float* a_r = (const float*)d_in[8];
  const float* b_r = (const float*)d_in[9];
  float* out = (float*)d_out;

  char* ws = (char*)d_ws;
  float* bias_ws = (float*)ws;                    // 16 KB
  __bf16* wb = (__bf16*)(ws + 16384);             // 384 KB
  __bf16* pwb = (__bf16*)(ws + 409600);           // 128 KB
  __bf16* xb = (__bf16*)(ws + 1048576);           // 64 MB (aliased as Ob later)
  __bf16* Vt = (__bf16*)(ws + 1048576 + 67108864);// 64 MB  -> ws use ~135 MB
  __bf16* Ob = xb;                                // xb dead after qkv_gemm
  __bf16* Qd = (__bf16*)d_out;                    // Q,K parked in out buffer
  __bf16* Kd = Qd + (size_t)NTOK * 256;           // dead before proj writes

  hipLaunchKernelGGL(prep_kernel, dim3(16528), dim3(256), 0, stream,
                     x, qkv_w, proj_w, theta_max, a_p, b_p, a_r, b_r,
                     xb, wb, pwb, bias_ws);
  hipLaunchKernelGGL(qkv_gemm_kernel, dim3(6, 1024), dim3(256), 0, stream,
                     xb, wb, qkv_b, Qd, Kd, Vt);
  hipLaunchKernelGGL(attn_kernel, dim3(2048), dim3(256), 0, stream,
                     Qd, Kd, Vt, bias_ws, Ob);
  hipLaunchKernelGGL(proj_gemm_kernel, dim3(2, 1024), dim3(256), 0, stream,
                     Ob, pwb, proj_b, out);
}